// Round 4
// baseline (445.224 us; speedup 1.0000x reference)
//
#include <hip/hip_runtime.h>
#include <hip/hip_fp16.h>
#include <math.h>

typedef _Float16 f16;
typedef unsigned int u32;
typedef _Float16 f16x8 __attribute__((ext_vector_type(8)));
typedef _Float16 f16x4 __attribute__((ext_vector_type(4)));
typedef float    f32x4 __attribute__((ext_vector_type(4)));

constexpr int LEN  = 512;
constexpr int HID  = 512;
constexpr int BATCH = 64;

#define BM 128
#define BN 128
#define BK 64

// ---- async global->LDS, 16B per lane. lds ptr must be wave-uniform. ----
__device__ __forceinline__ void gload16(const f16* g, f16* l) {
    __builtin_amdgcn_global_load_lds((const __attribute__((address_space(1))) u32*)g,
                                     (__attribute__((address_space(3))) u32*)l,
                                     16, 0, 0);
}

// ---- single bt-GEMM core: C[128x128] = A[128xK] * B[128xK]^T ----
__device__ __forceinline__ void gemm_core(const f16* __restrict__ A, int lda,
                                          const f16* __restrict__ Bm, int ldb,
                                          int ksteps,
                                          f16* ldsA, f16* ldsB,
                                          f32x4 acc[4][4])
{
    const int tid  = threadIdx.x;
    const int lane = tid & 63;
    const int wv   = tid >> 6;
    const int wr   = wv >> 1, wc = wv & 1;
    const int mf   = lane & 15;
    const int kf   = (lane >> 4) * 8;

    for (int r = 0; r < 4; ++r)
        for (int c = 0; c < 4; ++c)
            acc[r][c] = (f32x4){0.f, 0.f, 0.f, 0.f};

    for (int kt = 0; kt < ksteps; ++kt) {
        const int k0 = kt * BK;
        #pragma unroll
        for (int j = 0; j < 4; ++j) {
            const int cb  = j * 256 + wv * 64;
            const int c   = cb + lane;
            const int row = c >> 3;
            const int col = (c & 7) << 3;
            gload16(A  + (size_t)row * lda + (k0 + col), ldsA + cb * 8);
            gload16(Bm + (size_t)row * ldb + (k0 + col), ldsB + cb * 8);
        }
        __syncthreads();
        #pragma unroll
        for (int kk = 0; kk < BK; kk += 32) {
            f16x8 af[4], bf[4];
            #pragma unroll
            for (int r = 0; r < 4; ++r) {
                af[r] = *(const f16x8*)(ldsA + (wr * 64 + r * 16 + mf) * BK + kk + kf);
                bf[r] = *(const f16x8*)(ldsB + (wc * 64 + r * 16 + mf) * BK + kk + kf);
            }
            #pragma unroll
            for (int r = 0; r < 4; ++r)
                #pragma unroll
                for (int c = 0; c < 4; ++c)
                    acc[r][c] = __builtin_amdgcn_mfma_f32_16x16x32_f16(af[r], bf[c], acc[r][c], 0, 0, 0);
        }
        __syncthreads();
    }
}

// ---- dual bt-GEMM core: 3 staged tiles T0,T1,T2 ----
// acc1 = T0-a x T1-b ; acc2 = T[TA2]-a x T[TB2]-b
// qkproj: TA2=0,TB2=2 (shared A) ; zv: TA2=2,TB2=0 (cross)
template<int TA2, int TB2>
__device__ __forceinline__ void gemm_dual(const f16* __restrict__ g0, int ld0,
                                          const f16* __restrict__ g1, int ld1,
                                          const f16* __restrict__ g2, int ld2,
                                          int ksteps, f16* lds,
                                          f32x4 acc1[4][4], f32x4 acc2[4][4])
{
    const int tid  = threadIdx.x;
    const int lane = tid & 63;
    const int wv   = tid >> 6;
    const int wr   = wv >> 1, wc = wv & 1;
    const int mf   = lane & 15;
    const int kf   = (lane >> 4) * 8;
    f16* lds0 = lds;
    f16* lds1 = lds + BM * BK;
    f16* lds2 = lds + 2 * BM * BK;

    for (int r = 0; r < 4; ++r)
        for (int c = 0; c < 4; ++c) {
            acc1[r][c] = (f32x4){0.f, 0.f, 0.f, 0.f};
            acc2[r][c] = (f32x4){0.f, 0.f, 0.f, 0.f};
        }

    for (int kt = 0; kt < ksteps; ++kt) {
        const int k0 = kt * BK;
        #pragma unroll
        for (int j = 0; j < 4; ++j) {
            const int cb  = j * 256 + wv * 64;
            const int c   = cb + lane;
            const int row = c >> 3;
            const int col = (c & 7) << 3;
            gload16(g0 + (size_t)row * ld0 + (k0 + col), lds0 + cb * 8);
            gload16(g1 + (size_t)row * ld1 + (k0 + col), lds1 + cb * 8);
            gload16(g2 + (size_t)row * ld2 + (k0 + col), lds2 + cb * 8);
        }
        __syncthreads();
        #pragma unroll
        for (int kk = 0; kk < BK; kk += 32) {
            {   // ---- acc1 = T0 x T1 ----
                f16x8 af[4], bf[4];
                #pragma unroll
                for (int r = 0; r < 4; ++r) {
                    af[r] = *(const f16x8*)(lds0 + (wr * 64 + r * 16 + mf) * BK + kk + kf);
                    bf[r] = *(const f16x8*)(lds1 + (wc * 64 + r * 16 + mf) * BK + kk + kf);
                }
                #pragma unroll
                for (int r = 0; r < 4; ++r)
                    #pragma unroll
                    for (int c = 0; c < 4; ++c)
                        acc1[r][c] = __builtin_amdgcn_mfma_f32_16x16x32_f16(af[r], bf[c], acc1[r][c], 0, 0, 0);
            }
            {   // ---- acc2 = T[TA2] x T[TB2] ----
                const f16* la = (TA2 == 0) ? lds0 : lds2;
                const f16* lb = (TB2 == 0) ? lds0 : lds2;
                f16x8 af[4], bf[4];
                #pragma unroll
                for (int r = 0; r < 4; ++r) {
                    af[r] = *(const f16x8*)(la + (wr * 64 + r * 16 + mf) * BK + kk + kf);
                    bf[r] = *(const f16x8*)(lb + (wc * 64 + r * 16 + mf) * BK + kk + kf);
                }
                #pragma unroll
                for (int r = 0; r < 4; ++r)
                    #pragma unroll
                    for (int c = 0; c < 4; ++c)
                        acc2[r][c] = __builtin_amdgcn_mfma_f32_16x16x32_f16(af[r], bf[c], acc2[r][c], 0, 0, 0);
            }
        }
        __syncthreads();
    }
}

// C/D layout (16x16x32): col = lane&15, row = (lane>>4)*4 + reg   [m89-verified]
#define EPILOGUE_IDX() \
    const int lane = threadIdx.x & 63, wv_ = threadIdx.x >> 6;   \
    const int wr = wv_ >> 1, wc = wv_ & 1;                       \
    const int c0 = lane & 15, r0 = (lane >> 4) * 4;

// ---- vectorized f16 tile store: C-layout regs -> LDS -> coalesced f16x8 ----
__device__ __forceinline__ void store_tile_f16(f16* lds, const f16 vals[4][4][4],
                                               f16* __restrict__ gout, int ldo)
{
    const int tid = threadIdx.x;
    EPILOGUE_IDX();
    #pragma unroll
    for (int r = 0; r < 4; ++r)
        #pragma unroll
        for (int c = 0; c < 4; ++c)
            #pragma unroll
            for (int i = 0; i < 4; ++i) {
                const int lr = wr * 64 + r * 16 + r0 + i;
                const int lc = wc * 64 + c * 16 + c0;
                lds[lr * 128 + lc] = vals[r][c][i];
            }
    __syncthreads();
    #pragma unroll
    for (int ph = 0; ph < 8; ++ph) {
        const int row = ph * 16 + (tid >> 4);
        const int col = (tid & 15) * 8;
        *(f16x8*)(gout + (size_t)row * ldo + col) = *(const f16x8*)(lds + row * 128 + col);
    }
}

__device__ __forceinline__ float silu_f(float v) {
    return v * __builtin_amdgcn_rcpf(1.f + __expf(-v));
}

// ---- fused z | v^T: z = silu(x@Wz^T), vt = silu(Wv@x^T)  (vt born transposed) ----
__global__ __launch_bounds__(256) void k_zv(const f16* __restrict__ x,
                                            const f16* __restrict__ Wzh,
                                            const f16* __restrict__ Wvh,
                                            f16* __restrict__ z,
                                            f16* __restrict__ vt)
{
    __shared__ f16 lds[3 * BM * BK];
    f32x4 acc1[4][4], acc2[4][4];
    const int tn = blockIdx.x, tm = blockIdx.y;
    // T0 = x[tm], T1 = Wz[tn], T2 = Wv[tn]; acc1 = x*Wz^T, acc2 = Wv*x^T
    gemm_dual<2, 0>(x + (size_t)tm * BM * HID, HID,
                    Wzh + (size_t)tn * BN * HID, HID,
                    Wvh + (size_t)tn * BN * HID, HID,
                    HID / BK, lds, acc1, acc2);
    f16 vals[4][4][4];
    #pragma unroll
    for (int r = 0; r < 4; ++r)
        #pragma unroll
        for (int c = 0; c < 4; ++c)
            #pragma unroll
            for (int i = 0; i < 4; ++i)
                vals[r][c][i] = (f16)silu_f(acc1[r][c][i]);
    store_tile_f16(lds, vals, z + (size_t)tm * BM * HID + tn * BN, HID);
    __syncthreads();
    #pragma unroll
    for (int r = 0; r < 4; ++r)
        #pragma unroll
        for (int c = 0; c < 4; ++c)
            #pragma unroll
            for (int i = 0; i < 4; ++i)
                vals[r][c][i] = (f16)silu_f(acc2[r][c][i]);
    // acc2 rows = h-local (tn tile), cols = m-local (tm tile); tm = b*4 + mt
    const int b = tm >> 2, mt = tm & 3;
    store_tile_f16(lds, vals,
                   vt + (size_t)b * LEN * HID + (size_t)tn * BN * LEN + mt * BM, LEN);
}

// ---- fused q | k: q = (z@Wq^T)*gq+bq, k = (z@Wk^T)*gk+bk, x1024 lift ----
__global__ __launch_bounds__(256) void k_qkproj(const f16* __restrict__ z,
                                                const f16* __restrict__ Wqh,
                                                const f16* __restrict__ Wkh,
                                                const float* __restrict__ gq,
                                                const float* __restrict__ bq,
                                                const float* __restrict__ gk,
                                                const float* __restrict__ bk,
                                                f16* __restrict__ qh,
                                                f16* __restrict__ kh)
{
    __shared__ f16 lds[3 * BM * BK];
    f32x4 acc1[4][4], acc2[4][4];
    const int tn = blockIdx.x, tm = blockIdx.y;
    // T0 = z[tm], T1 = Wq[tn], T2 = Wk[tn]; shared A
    gemm_dual<0, 2>(z + (size_t)tm * BM * HID, HID,
                    Wqh + (size_t)tn * BN * HID, HID,
                    Wkh + (size_t)tn * BN * HID, HID,
                    HID / BK, lds, acc1, acc2);
    f16 vals[4][4][4];
    {
        EPILOGUE_IDX();
        #pragma unroll
        for (int r = 0; r < 4; ++r)
            #pragma unroll
            for (int c = 0; c < 4; ++c) {
                const int gj = tn * BN + wc * 64 + c * 16 + c0;
                const float ga = gq[gj], ba = bq[gj];
                #pragma unroll
                for (int i = 0; i < 4; ++i)
                    vals[r][c][i] = (f16)((acc1[r][c][i] * ga + ba) * 1024.f);
            }
    }
    store_tile_f16(lds, vals, qh + (size_t)tm * BM * HID + tn * BN, HID);
    __syncthreads();
    {
        EPILOGUE_IDX();
        #pragma unroll
        for (int r = 0; r < 4; ++r)
            #pragma unroll
            for (int c = 0; c < 4; ++c) {
                const int gj = tn * BN + wc * 64 + c * 16 + c0;
                const float ga = gk[gj], ba = bk[gj];
                #pragma unroll
                for (int i = 0; i < 4; ++i)
                    vals[r][c][i] = (f16)((acc2[r][c][i] * ga + ba) * 1024.f);
            }
    }
    store_tile_f16(lds, vals, kh + (size_t)tm * BM * HID + tn * BN, HID);
}

// ---- batched q@k^T + mask + smask + relu^2 -> p (fp16), compact triangular grid ----
__constant__ int LT_TAB[10] = {0,1,1,2,2,2,3,3,3,3};
__constant__ int MT_TAB[10] = {0,0,1,0,1,2,0,1,2,3};

__global__ __launch_bounds__(256) void k_qk(const f16* __restrict__ q,
                                            const f16* __restrict__ kmat,
                                            const int* __restrict__ mask,
                                            const float* __restrict__ smask,
                                            f16* __restrict__ p)
{
    const int lt = LT_TAB[blockIdx.x], mt = MT_TAB[blockIdx.x], b = blockIdx.y;
    __shared__ f16 lds[(BM + BN) * BK];
    f32x4 acc[4][4];
    const size_t boff = (size_t)b * LEN * HID;
    gemm_core(q + boff + (size_t)lt * BM * HID, HID,
              kmat + boff + (size_t)mt * BN * HID, HID,
              HID / BK, lds, lds + BM * BK, acc);
    f16 vals[4][4][4];
    {
        EPILOGUE_IDX();
        #pragma unroll
        for (int r = 0; r < 4; ++r)
            #pragma unroll
            for (int c = 0; c < 4; ++c) {
                const int m = mt * BN + wc * 64 + c * 16 + c0;
                const int keepcol = mask[b * LEN + m];
                #pragma unroll
                for (int i = 0; i < 4; ++i) {
                    const int l = lt * BM + wr * 64 + r * 16 + r0 + i;
                    const bool keep = (l == m) || ((m <= l) && (keepcol != 0));
                    float v = keep ? acc[r][c][i] * smask[l * LEN + m] : 0.f;
                    v = fmaxf(v, 0.f);
                    vals[r][c][i] = (f16)(v * v);
                }
            }
    }
    store_tile_f16(lds, vals, p + (size_t)b * LEN * LEN + (size_t)lt * BM * LEN + mt * BN, LEN);
}

// ---- batched p@v (vt) -> out f32, causal K truncation; long blocks first ----
__global__ __launch_bounds__(256) void k_pv(const f16* __restrict__ p,
                                            const f16* __restrict__ vt,
                                            float* __restrict__ out)
{
    const int ht = blockIdx.x, lt = 3 - blockIdx.y, b = blockIdx.z;
    __shared__ f16 lds[(BM + BN) * BK];
    f32x4 acc[4][4];
    gemm_core(p + (size_t)b * LEN * LEN + (size_t)lt * BM * LEN, LEN,
              vt + (size_t)b * HID * LEN + (size_t)ht * BN * LEN, LEN,
              (lt + 1) * BM / BK, lds, lds + BM * BK, acc);
    EPILOGUE_IDX();
    // undo q,k 2^10 lifts (squared -> 2^40) and /(L*H)=2^18 : 2^-58 exact
    const float SCALE = 3.4694469519536142e-18f;
    #pragma unroll
    for (int r = 0; r < 4; ++r)
        #pragma unroll
        for (int c = 0; c < 4; ++c) {
            const int h = ht * BN + wc * 64 + c * 16 + c0;
            #pragma unroll
            for (int i = 0; i < 4; ++i) {
                const int l = lt * BM + wr * 64 + r * 16 + r0 + i;
                out[(size_t)b * LEN * HID + (size_t)l * HID + h] = acc[r][c][i] * SCALE;
            }
        }
}

// ---- one prep launch: gather(x) + 4x weight f2h + smask ----
__global__ __launch_bounds__(256) void k_prep(const int* __restrict__ pos,
                                              const float* __restrict__ item_emb,
                                              const float* __restrict__ pos_emb,
                                              f16* __restrict__ x,
                                              const float* __restrict__ Wz,
                                              const float* __restrict__ Wv,
                                              const float* __restrict__ Wq,
                                              const float* __restrict__ Wk,
                                              f16* __restrict__ Wzh,
                                              f16* __restrict__ Wvh,
                                              f16* __restrict__ Wqh,
                                              f16* __restrict__ Wkh,
                                              const float* __restrict__ sw,
                                              const float* __restrict__ gum,
                                              float* __restrict__ smask)
{
    const int bid = blockIdx.x;
    const int tid = threadIdx.x;
    if (bid < 16384) {                       // gather: x = item_emb[pos] + pos_emb
        const int t = bid * 256 + tid;
        const int i = t >> 7;
        const int c = t & 127;
        const int l = i & (LEN - 1);
        const int item = pos[i];
        const float4 a  = ((const float4*)(item_emb + (size_t)item * HID))[c];
        const float4 b4 = ((const float4*)(pos_emb + (size_t)l * HID))[c];
        f16x4 o = { (f16)(a.x + b4.x), (f16)(a.y + b4.y),
                    (f16)(a.z + b4.z), (f16)(a.w + b4.w) };
        *(f16x4*)(x + (size_t)t * 4) = o;
    } else if (bid < 16384 + 1024) {         // weight f32 -> f16
        const int r = bid - 16384;
        const int w = r >> 8;
        const float* s = (w == 0) ? Wz : (w == 1) ? Wv : (w == 2) ? Wq : Wk;
        f16* d = (w == 0) ? Wzh : (w == 1) ? Wvh : (w == 2) ? Wqh : Wkh;
        const int t = (r & 255) * 256 + tid;
        const float4 v = ((const float4*)s)[t];
        f16x4 o = { (f16)v.x, (f16)v.y, (f16)v.z, (f16)v.w };
        *(f16x4*)(d + (size_t)t * 4) = o;
    } else {                                 // gumbel-sigmoid smask (fp32)
        const int t = (bid - 16384 - 1024) * 256 + tid;
        const float4 w4 = ((const float4*)sw)[t];
        const float4 g4 = ((const float4*)gum)[t];
        float4 o;
        o.x = __builtin_amdgcn_rcpf(1.f + __expf(-(__logf(w4.x / (1.f - w4.x)) + g4.x) * 5.f));
        o.y = __builtin_amdgcn_rcpf(1.f + __expf(-(__logf(w4.y / (1.f - w4.y)) + g4.y) * 5.f));
        o.z = __builtin_amdgcn_rcpf(1.f + __expf(-(__logf(w4.z / (1.f - w4.z)) + g4.z) * 5.f));
        o.w = __builtin_amdgcn_rcpf(1.f + __expf(-(__logf(w4.w / (1.f - w4.w)) + g4.w) * 5.f));
        ((float4*)smask)[t] = o;
    }
}

extern "C" void kernel_launch(void* const* d_in, const int* in_sizes, int n_in,
                              void* d_out, int out_size, void* d_ws, size_t ws_size,
                              hipStream_t stream)
{
    const int*   positives = (const int*)  d_in[0];
    const int*   mask      = (const int*)  d_in[1];
    const float* item_emb  = (const float*)d_in[2];
    const float* pos_emb   = (const float*)d_in[3];
    const float* Wz        = (const float*)d_in[4];
    const float* Wv        = (const float*)d_in[5];
    const float* Wq        = (const float*)d_in[6];
    const float* Wk        = (const float*)d_in[7];
    const float* gamma_q   = (const float*)d_in[8];
    const float* beta_q    = (const float*)d_in[9];
    const float* gamma_k   = (const float*)d_in[10];
    const float* beta_k    = (const float*)d_in[11];
    const float* sparse_w  = (const float*)d_in[12];
    const float* gumbel    = (const float*)d_in[13];
    float* out = (float*)d_out;

    char* ws = (char*)d_ws;
    const size_t BUFB = (size_t)BATCH * LEN * HID * sizeof(f16);  // 32 MB
    f16* buf0 = (f16*)ws;                // x  -> p
    f16* buf1 = (f16*)(ws + BUFB);       // z
    f16* buf2 = (f16*)(ws + 2 * BUFB);   // vt
    f16* Wzh  = (f16*)(ws + 3 * BUFB);
    f16* Wvh  = Wzh + LEN * HID;
    f16* Wqh  = Wvh + LEN * HID;
    f16* Wkh  = Wqh + LEN * HID;
    float* smask = (float*)(Wkh + LEN * HID);
    // q,k live in d_out (exactly 2 x 32MB fp16) until k_pv overwrites it
    f16* qh = (f16*)d_out;
    f16* kh = qh + (size_t)BATCH * LEN * HID;

    k_prep<<<16384 + 1024 + 256, 256, 0, stream>>>(
        positives, item_emb, pos_emb, buf0,
        Wz, Wv, Wq, Wk, Wzh, Wvh, Wqh, Wkh,
        sparse_w, gumbel, smask);

    k_zv<<<dim3(4, 256), 256, 0, stream>>>(buf0, Wzh, Wvh, buf1, buf2);

    k_qkproj<<<dim3(4, 256), 256, 0, stream>>>(buf1, Wqh, Wkh,
                                               gamma_q, beta_q, gamma_k, beta_k,
                                               qh, kh);

    k_qk<<<dim3(10, 64), 256, 0, stream>>>(qh, kh, mask, smask, buf0);

    k_pv<<<dim3(4, 4, BATCH), 256, 0, stream>>>(buf0, buf2, out);
}

// Round 5
// 372.814 us; speedup vs baseline: 1.1942x; 1.1942x over previous
//
#include <hip/hip_runtime.h>
#include <hip/hip_fp16.h>
#include <math.h>

typedef _Float16 f16;
typedef unsigned int u32;
typedef _Float16 f16x8 __attribute__((ext_vector_type(8)));
typedef _Float16 f16x4 __attribute__((ext_vector_type(4)));
typedef float    f32x4 __attribute__((ext_vector_type(4)));

constexpr int LEN  = 512;
constexpr int HID  = 512;
constexpr int BATCH = 64;

#define BM 128
#define BN 128
#define BK 64

// ---- async global->LDS, 16B per lane. lds ptr must be wave-uniform. ----
__device__ __forceinline__ void gload16(const f16* g, f16* l) {
    __builtin_amdgcn_global_load_lds((const __attribute__((address_space(1))) u32*)g,
                                     (__attribute__((address_space(3))) u32*)l,
                                     16, 0, 0);
}

// ---- single bt-GEMM core: C[128x128] = A[128xK] * B[128xK]^T ----
// 88 VGPR / 32KB LDS -> 5 blocks/CU resident (the R4 dual-acc variant at 160/48K
// dropped to 3 blocks/CU and regressed -- keep this core single-acc).
__device__ __forceinline__ void gemm_core(const f16* __restrict__ A, int lda,
                                          const f16* __restrict__ Bm, int ldb,
                                          int ksteps,
                                          f16* ldsA, f16* ldsB,
                                          f32x4 acc[4][4])
{
    const int tid  = threadIdx.x;
    const int lane = tid & 63;
    const int wv   = tid >> 6;
    const int wr   = wv >> 1, wc = wv & 1;
    const int mf   = lane & 15;
    const int kf   = (lane >> 4) * 8;

    for (int r = 0; r < 4; ++r)
        for (int c = 0; c < 4; ++c)
            acc[r][c] = (f32x4){0.f, 0.f, 0.f, 0.f};

    for (int kt = 0; kt < ksteps; ++kt) {
        const int k0 = kt * BK;
        #pragma unroll
        for (int j = 0; j < 4; ++j) {
            const int cb  = j * 256 + wv * 64;
            const int c   = cb + lane;
            const int row = c >> 3;
            const int col = (c & 7) << 3;
            gload16(A  + (size_t)row * lda + (k0 + col), ldsA + cb * 8);
            gload16(Bm + (size_t)row * ldb + (k0 + col), ldsB + cb * 8);
        }
        __syncthreads();
        #pragma unroll
        for (int kk = 0; kk < BK; kk += 32) {
            f16x8 af[4], bf[4];
            #pragma unroll
            for (int r = 0; r < 4; ++r) {
                af[r] = *(const f16x8*)(ldsA + (wr * 64 + r * 16 + mf) * BK + kk + kf);
                bf[r] = *(const f16x8*)(ldsB + (wc * 64 + r * 16 + mf) * BK + kk + kf);
            }
            #pragma unroll
            for (int r = 0; r < 4; ++r)
                #pragma unroll
                for (int c = 0; c < 4; ++c)
                    acc[r][c] = __builtin_amdgcn_mfma_f32_16x16x32_f16(af[r], bf[c], acc[r][c], 0, 0, 0);
        }
        __syncthreads();
    }
}

// C/D layout (16x16x32): col = lane&15, row = (lane>>4)*4 + reg   [m89-verified]
#define EPILOGUE_IDX() \
    const int lane = threadIdx.x & 63, wv_ = threadIdx.x >> 6;   \
    const int wr = wv_ >> 1, wc = wv_ & 1;                       \
    const int c0 = lane & 15, r0 = (lane >> 4) * 4;

// ---- vectorized f16 tile store: C-layout regs -> LDS -> coalesced f16x8 ----
__device__ __forceinline__ void store_tile_f16(f16* lds, const f16 vals[4][4][4],
                                               f16* __restrict__ gout, int ldo)
{
    const int tid = threadIdx.x;
    EPILOGUE_IDX();
    #pragma unroll
    for (int r = 0; r < 4; ++r)
        #pragma unroll
        for (int c = 0; c < 4; ++c)
            #pragma unroll
            for (int i = 0; i < 4; ++i) {
                const int lr = wr * 64 + r * 16 + r0 + i;
                const int lc = wc * 64 + c * 16 + c0;
                lds[lr * 128 + lc] = vals[r][c][i];
            }
    __syncthreads();
    #pragma unroll
    for (int ph = 0; ph < 8; ++ph) {
        const int row = ph * 16 + (tid >> 4);
        const int col = (tid & 15) * 8;
        *(f16x8*)(gout + (size_t)row * ldo + col) = *(const f16x8*)(lds + row * 128 + col);
    }
}

__device__ __forceinline__ float silu_f(float v) {
    return v * __builtin_amdgcn_rcpf(1.f + __expf(-v));
}

// ---- fused z | v^T, XCD-swizzled ----
// 2048 blocks. slab s (x rows s*128..s*128+127) has 8 consumer blocks:
// z (tn=0..3) and vt (ht=0..3). bid = (s%8) + 8*i + 64*(s/8) puts all 8
// consumers on one XCD (bid%8 const) within a 64-bid window.
__global__ __launch_bounds__(256) void k_zv(const f16* __restrict__ x,
                                            const f16* __restrict__ Wzh,
                                            const f16* __restrict__ Wvh,
                                            f16* __restrict__ z,
                                            f16* __restrict__ vt)
{
    const int bid = blockIdx.x;
    const int s = (bid & 7) + 8 * (bid >> 6);      // x-slab 0..255
    const int i = (bid >> 3) & 7;                  // consumer 0..7
    __shared__ f16 lds[(BM + BN) * BK];
    f32x4 acc[4][4];
    f16 vals[4][4][4];
    if (i < 4) {           // z[s, tn=i] = silu(x_s @ Wz_i^T)
        gemm_core(x + (size_t)s * BM * HID, HID,
                  Wzh + (size_t)i * BN * HID, HID,
                  HID / BK, lds, lds + BM * BK, acc);
        #pragma unroll
        for (int r = 0; r < 4; ++r)
            #pragma unroll
            for (int c = 0; c < 4; ++c)
                #pragma unroll
                for (int q = 0; q < 4; ++q)
                    vals[r][c][q] = (f16)silu_f(acc[r][c][q]);
        store_tile_f16(lds, vals, z + (size_t)s * BM * HID + i * BN, HID);
    } else {               // vt[b, ht=i-4, mt] = silu(Wv_ht @ x_{b,mt}^T)
        const int ht = i - 4, b = s >> 2, mt = s & 3;
        gemm_core(Wvh + (size_t)ht * BM * HID, HID,
                  x + ((size_t)b * LEN + mt * BN) * HID, HID,
                  HID / BK, lds, lds + BM * BK, acc);
        #pragma unroll
        for (int r = 0; r < 4; ++r)
            #pragma unroll
            for (int c = 0; c < 4; ++c)
                #pragma unroll
                for (int q = 0; q < 4; ++q)
                    vals[r][c][q] = (f16)silu_f(acc[r][c][q]);
        store_tile_f16(lds, vals,
                       vt + (size_t)b * LEN * HID + (size_t)ht * BM * LEN + mt * BN, LEN);
    }
}

// ---- fused q | k projections, same swizzle over z-slabs ----
__global__ __launch_bounds__(256) void k_qkp(const f16* __restrict__ z,
                                             const f16* __restrict__ Wqh,
                                             const f16* __restrict__ Wkh,
                                             const float* __restrict__ gq,
                                             const float* __restrict__ bq,
                                             const float* __restrict__ gk,
                                             const float* __restrict__ bk,
                                             f16* __restrict__ qh,
                                             f16* __restrict__ kh)
{
    const int bid = blockIdx.x;
    const int s = (bid & 7) + 8 * (bid >> 6);
    const int i = (bid >> 3) & 7;
    const bool isq = i < 4;
    const int tn = isq ? i : i - 4;
    const f16* W = isq ? Wqh : Wkh;
    const float* g = isq ? gq : gk;
    const float* be = isq ? bq : bk;
    f16* out = isq ? qh : kh;
    __shared__ f16 lds[(BM + BN) * BK];
    f32x4 acc[4][4];
    gemm_core(z + (size_t)s * BM * HID, HID,
              W + (size_t)tn * BN * HID, HID,
              HID / BK, lds, lds + BM * BK, acc);
    f16 vals[4][4][4];
    {
        EPILOGUE_IDX();
        #pragma unroll
        for (int r = 0; r < 4; ++r)
            #pragma unroll
            for (int c = 0; c < 4; ++c) {
                const int gj = tn * BN + wc * 64 + c * 16 + c0;
                const float ga = g[gj], ba = be[gj];
                #pragma unroll
                for (int q = 0; q < 4; ++q)
                    vals[r][c][q] = (f16)((acc[r][c][q] * ga + ba) * 1024.f);
            }
    }
    store_tile_f16(lds, vals, out + (size_t)s * BM * HID + tn * BN, HID);
}

// ---- batched q@k^T + mask + smask + relu^2 -> p, triangular, per-batch XCD ----
// 640 blocks: batch b's 10 tri-tiles at bid = (b%8) + 8*(t + 10*(b/8))
__constant__ int LT_TAB[10] = {0,1,1,2,2,2,3,3,3,3};
__constant__ int MT_TAB[10] = {0,0,1,0,1,2,0,1,2,3};

__global__ __launch_bounds__(256) void k_qk(const f16* __restrict__ q,
                                            const f16* __restrict__ kmat,
                                            const int* __restrict__ mask,
                                            const float* __restrict__ smask,
                                            f16* __restrict__ p)
{
    const int bid = blockIdx.x;
    const int t = (bid >> 3) % 10;
    const int b = (bid & 7) + 8 * (bid / 80);
    const int lt = LT_TAB[t], mt = MT_TAB[t];
    __shared__ f16 lds[(BM + BN) * BK];
    f32x4 acc[4][4];
    const size_t boff = (size_t)b * LEN * HID;
    gemm_core(q + boff + (size_t)lt * BM * HID, HID,
              kmat + boff + (size_t)mt * BN * HID, HID,
              HID / BK, lds, lds + BM * BK, acc);
    f16 vals[4][4][4];
    {
        EPILOGUE_IDX();
        #pragma unroll
        for (int r = 0; r < 4; ++r)
            #pragma unroll
            for (int c = 0; c < 4; ++c) {
                const int m = mt * BN + wc * 64 + c * 16 + c0;
                const int keepcol = mask[b * LEN + m];
                #pragma unroll
                for (int i = 0; i < 4; ++i) {
                    const int l = lt * BM + wr * 64 + r * 16 + r0 + i;
                    const bool keep = (l == m) || ((m <= l) && (keepcol != 0));
                    float v = keep ? acc[r][c][i] * smask[l * LEN + m] : 0.f;
                    v = fmaxf(v, 0.f);
                    vals[r][c][i] = (f16)(v * v);
                }
            }
    }
    store_tile_f16(lds, vals, p + (size_t)b * LEN * LEN + (size_t)lt * BM * LEN + mt * BN, LEN);
}

// ---- batched p@v -> out f32; per-batch XCD grouping (p re-read hits the
// same L2 that k_qk wrote); causal K truncation; long lt first ----
// 1024 blocks: bid = (b%8) + 8*(inner + 16*(b/8)), inner = (3-lt)*4 + ht
__global__ __launch_bounds__(256) void k_pv(const f16* __restrict__ p,
                                            const f16* __restrict__ vt,
                                            float* __restrict__ out)
{
    const int bid = blockIdx.x;
    const int inner = (bid >> 3) & 15;
    const int b = (bid & 7) + 8 * (bid >> 7);
    const int lt = 3 - (inner >> 2), ht = inner & 3;
    __shared__ f16 lds[(BM + BN) * BK];
    f32x4 acc[4][4];
    gemm_core(p + (size_t)b * LEN * LEN + (size_t)lt * BM * LEN, LEN,
              vt + (size_t)b * HID * LEN + (size_t)ht * BN * LEN, LEN,
              (lt + 1) * BM / BK, lds, lds + BM * BK, acc);
    EPILOGUE_IDX();
    // undo q,k 2^10 lifts (squared -> 2^40) and /(L*H)=2^18 : 2^-58 exact
    const float SCALE = 3.4694469519536142e-18f;
    #pragma unroll
    for (int r = 0; r < 4; ++r)
        #pragma unroll
        for (int c = 0; c < 4; ++c) {
            const int h = ht * BN + wc * 64 + c * 16 + c0;
            #pragma unroll
            for (int i = 0; i < 4; ++i) {
                const int l = lt * BM + wr * 64 + r * 16 + r0 + i;
                out[(size_t)b * LEN * HID + (size_t)l * HID + h] = acc[r][c][i] * SCALE;
            }
        }
}

// ---- one prep launch: gather(x) + 4x weight f2h + smask ----
__global__ __launch_bounds__(256) void k_prep(const int* __restrict__ pos,
                                              const float* __restrict__ item_emb,
                                              const float* __restrict__ pos_emb,
                                              f16* __restrict__ x,
                                              const float* __restrict__ Wz,
                                              const float* __restrict__ Wv,
                                              const float* __restrict__ Wq,
                                              const float* __restrict__ Wk,
                                              f16* __restrict__ Wzh,
                                              f16* __restrict__ Wvh,
                                              f16* __restrict__ Wqh,
                                              f16* __restrict__ Wkh,
                                              const float* __restrict__ sw,
                                              const float* __restrict__ gum,
                                              float* __restrict__ smask)
{
    const int bid = blockIdx.x;
    const int tid = threadIdx.x;
    if (bid < 16384) {                       // gather: x = item_emb[pos] + pos_emb
        const int t = bid * 256 + tid;
        const int i = t >> 7;
        const int c = t & 127;
        const int l = i & (LEN - 1);
        const int item = pos[i];
        const float4 a  = ((const float4*)(item_emb + (size_t)item * HID))[c];
        const float4 b4 = ((const float4*)(pos_emb + (size_t)l * HID))[c];
        f16x4 o = { (f16)(a.x + b4.x), (f16)(a.y + b4.y),
                    (f16)(a.z + b4.z), (f16)(a.w + b4.w) };
        *(f16x4*)(x + (size_t)t * 4) = o;
    } else if (bid < 16384 + 1024) {         // weight f32 -> f16
        const int r = bid - 16384;
        const int w = r >> 8;
        const float* s = (w == 0) ? Wz : (w == 1) ? Wv : (w == 2) ? Wq : Wk;
        f16* d = (w == 0) ? Wzh : (w == 1) ? Wvh : (w == 2) ? Wqh : Wkh;
        const int t = (r & 255) * 256 + tid;
        const float4 v = ((const float4*)s)[t];
        f16x4 o = { (f16)v.x, (f16)v.y, (f16)v.z, (f16)v.w };
        *(f16x4*)(d + (size_t)t * 4) = o;
    } else {                                 // gumbel-sigmoid smask (fp32)
        const int t = (bid - 16384 - 1024) * 256 + tid;
        const float4 w4 = ((const float4*)sw)[t];
        const float4 g4 = ((const float4*)gum)[t];
        float4 o;
        o.x = __builtin_amdgcn_rcpf(1.f + __expf(-(__logf(w4.x / (1.f - w4.x)) + g4.x) * 5.f));
        o.y = __builtin_amdgcn_rcpf(1.f + __expf(-(__logf(w4.y / (1.f - w4.y)) + g4.y) * 5.f));
        o.z = __builtin_amdgcn_rcpf(1.f + __expf(-(__logf(w4.z / (1.f - w4.z)) + g4.z) * 5.f));
        o.w = __builtin_amdgcn_rcpf(1.f + __expf(-(__logf(w4.w / (1.f - w4.w)) + g4.w) * 5.f));
        ((float4*)smask)[t] = o;
    }
}

extern "C" void kernel_launch(void* const* d_in, const int* in_sizes, int n_in,
                              void* d_out, int out_size, void* d_ws, size_t ws_size,
                              hipStream_t stream)
{
    const int*   positives = (const int*)  d_in[0];
    const int*   mask      = (const int*)  d_in[1];
    const float* item_emb  = (const float*)d_in[2];
    const float* pos_emb   = (const float*)d_in[3];
    const float* Wz        = (const float*)d_in[4];
    const float* Wv        = (const float*)d_in[5];
    const float* Wq        = (const float*)d_in[6];
    const float* Wk        = (const float*)d_in[7];
    const float* gamma_q   = (const float*)d_in[8];
    const float* beta_q    = (const float*)d_in[9];
    const float* gamma_k   = (const float*)d_in[10];
    const float* beta_k    = (const float*)d_in[11];
    const float* sparse_w  = (const float*)d_in[12];
    const float* gumbel    = (const float*)d_in[13];
    float* out = (float*)d_out;

    char* ws = (char*)d_ws;
    const size_t BUFB = (size_t)BATCH * LEN * HID * sizeof(f16);  // 32 MB
    f16* buf0 = (f16*)ws;                // x  -> p
    f16* buf1 = (f16*)(ws + BUFB);       // z
    f16* buf2 = (f16*)(ws + 2 * BUFB);   // vt
    f16* Wzh  = (f16*)(ws + 3 * BUFB);
    f16* Wvh  = Wzh + LEN * HID;
    f16* Wqh  = Wvh + LEN * HID;
    f16* Wkh  = Wqh + LEN * HID;
    float* smask = (float*)(Wkh + LEN * HID);
    // q,k live in d_out (exactly 2 x 32MB fp16) until k_pv overwrites it
    f16* qh = (f16*)d_out;
    f16* kh = qh + (size_t)BATCH * LEN * HID;

    k_prep<<<16384 + 1024 + 256, 256, 0, stream>>>(
        positives, item_emb, pos_emb, buf0,
        Wz, Wv, Wq, Wk, Wzh, Wvh, Wqh, Wkh,
        sparse_w, gumbel, smask);

    k_zv<<<2048, 256, 0, stream>>>(buf0, Wzh, Wvh, buf1, buf2);

    k_qkp<<<2048, 256, 0, stream>>>(buf1, Wqh, Wkh,
                                    gamma_q, beta_q, gamma_k, beta_k, qh, kh);

    k_qk<<<640, 256, 0, stream>>>(qh, kh, mask, smask, buf0);

    k_pv<<<1024, 256, 0, stream>>>(buf0, buf2, out);
}